// Round 11
// baseline (79474.915 us; speedup 1.0000x reference)
//
#include <hip/hip_runtime.h>
#include <math.h>

#define NN 256
#define HH 64

typedef unsigned int uint32;
typedef __attribute__((ext_vector_type(8))) short bf16x8;
typedef __attribute__((ext_vector_type(4))) float f32x4;

__device__ __forceinline__ float sigm(float x) { return 1.0f / (1.0f + expf(-x)); }

// f32 -> bf16 (RNE) in low 16 bits
__device__ __forceinline__ uint32 f2bf(float f) {
    uint32 u = __float_as_uint(f);
    return (u + 0x7fffu + ((u >> 16) & 1u)) >> 16;
}

// ---------------- R construction (fp64 GEMM chain) — proven ----------------
__global__ void k_affine(const float* __restrict__ A, float* __restrict__ Pout,
                         const float* __restrict__ tev, int div)
{
    int i = blockIdx.x, j = threadIdx.x;
    double h = (double)tev[1] - (double)tev[0];
    double v = (i == j ? 1.0 : 0.0) + (h / (double)div) * (double)A[i * NN + j];
    Pout[i * NN + j] = (float)v;
}

__global__ void k_gemm(const float* __restrict__ A, const float* __restrict__ Pin,
                       float* __restrict__ Pout, const float* __restrict__ tev, int div)
{
    int i = blockIdx.x, j = threadIdx.x;
    double h = (double)tev[1] - (double)tev[0];
    const float* Ar = A + i * NN;
    double acc = 0.0;
    for (int k = 0; k < NN; ++k) acc += (double)Ar[k] * (double)Pin[k * NN + j];
    double v = (i == j ? 1.0 : 0.0) + (h / (double)div) * acc;
    Pout[i * NN + j] = (float)v;
}

// gq = [g0 | g1 | g2 | g3 | q | ce]  (ce = MU * rowsum(R - I), fp64) — proven
__global__ void k_prep_vec(const float* __restrict__ A, const float* __restrict__ B,
                           const float* __restrict__ cooling, const float* __restrict__ tev,
                           const float* __restrict__ R, float* __restrict__ gq)
{
    __shared__ float heat[NN];
    __shared__ float vin[NN];
    int t = threadIdx.x;
    double h = (double)tev[1] - (double)tev[0];
    heat[t] = (t < NN - 2) ? 500.0f * sigm(cooling[t]) : 0.0f;
    __syncthreads();
    float B0 = B[t * (NN - 1)];
    double bh = 0.0;
    for (int j = 0; j < NN - 2; ++j) bh += (double)B[t * (NN - 1) + 1 + j] * (double)heat[j];
    vin[t] = B0; __syncthreads();
    double v1 = 0.0; for (int k = 0; k < NN; ++k) v1 += (double)A[t * NN + k] * (double)vin[k];
    __syncthreads(); vin[t] = (float)v1; __syncthreads();
    double v2 = 0.0; for (int k = 0; k < NN; ++k) v2 += (double)A[t * NN + k] * (double)vin[k];
    __syncthreads(); vin[t] = (float)v2; __syncthreads();
    double v3 = 0.0; for (int k = 0; k < NN; ++k) v3 += (double)A[t * NN + k] * (double)vin[k];
    __syncthreads();
    vin[t] = (float)bh; __syncthreads();
    double u1 = 0.0; for (int k = 0; k < NN; ++k) u1 += (double)A[t * NN + k] * (double)vin[k];
    __syncthreads(); vin[t] = (float)u1; __syncthreads();
    double u2 = 0.0; for (int k = 0; k < NN; ++k) u2 += (double)A[t * NN + k] * (double)vin[k];
    __syncthreads(); vin[t] = (float)u2; __syncthreads();
    double u3 = 0.0; for (int k = 0; k < NN; ++k) u3 += (double)A[t * NN + k] * (double)vin[k];

    double srow = 0.0;
    for (int c = 0; c < NN; ++c) srow += (double)R[t * NN + c];
    srow -= 1.0;                               // rowsum(E)

    gq[t]        = (float)((h / 6.0) * (double)B0);
    gq[256 + t]  = (float)((h * h / 6.0) * v1);
    gq[512 + t]  = (float)((h * h * h / 12.0) * v2);
    gq[768 + t]  = (float)((h * h * h * h / 24.0) * v3);
    gq[1024 + t] = (float)(h * bh + (h * h / 2.0) * u1 + (h * h * h / 6.0) * u2
                           + (h * h * h * h / 24.0) * u3);
    gq[1280 + t] = (float)(23.359 * srow);
}

__device__ __forceinline__ float interp1(float x, const float* __restrict__ ts,
                                         const float* __restrict__ vs, int n)
{
    int lo = 0, hi = n;
    while (lo < hi) { int mid = (lo + hi) >> 1; if (ts[mid] <= x) lo = mid + 1; else hi = mid; }
    int i = lo; if (i < 1) i = 1; if (i > n - 1) i = n - 1;
    float xim = ts[i - 1], xi = ts[i];
    float fim = vs[i - 1], fi = vs[i];
    return fim + (x - xim) / (xi - xim) * (fi - fim);
}

// td[k][0..7] = {S0,S1,S2,S3, sinD,cosD,sinW,cosW} — proven
__global__ void k_time(const float* __restrict__ tev, const float* __restrict__ tts,
                       const float* __restrict__ tvals, float* __restrict__ td,
                       int T, int ntout)
{
    int k = blockIdx.x * blockDim.x + threadIdx.x;
    if (k >= T) return;
    float t0 = tev[0];
    float dtf = tev[1] - t0;
    float t = tev[k] - t0;
    const float cD = (float)(2.0 * M_PI / 86400.0);
    const float cW = (float)(2.0 * M_PI / 604800.0);
    float f0 = (float)sin((double)(t * cD));
    float f1 = (float)cos((double)(t * cD));
    float f2 = (float)sin((double)(t * cW));
    float f3 = (float)cos((double)(t * cW));
    float To1 = interp1(t + t0, tts, tvals, ntout);
    float To2 = interp1((t + 0.5f * dtf) + t0, tts, tvals, ntout);
    float To4 = interp1((t + dtf) + t0, tts, tvals, ntout);
    size_t o = (size_t)k * 8;
    td[o + 0] = To1 + 4.0f * To2 + To4;
    td[o + 1] = To1 + 2.0f * To2;
    td[o + 2] = To1 + To2;
    td[o + 3] = To1;
    td[o + 4] = f0; td[o + 5] = f1; td[o + 6] = f2; td[o + 7] = f3;
}

// Pack E = R - I (bf16) as MFMA A-fragments for v_mfma_f32_16x16x32_bf16.
// Assumed A map: lane l holds A[m][k], m = l&15, k = (l>>4)*8 + j (j=0..7).
// Thread t of k_main = wave w (=t>>6) tile rows [16w,16w+16), lane l=t&63.
// Epk dword d: t=d>>5, kt=(d&31)>>2, dw=d&3 -> elems j=2dw,2dw+1 of K-tile kt.
// (If absmax explodes: alternate map variant is k0 = kt*32 + dw*8 + (l>>4)*2.)
__global__ void k_packE(const float* __restrict__ R, uint32* __restrict__ Epk)
{
    int d = blockIdx.x * 256 + threadIdx.x;   // 0..32767
    int t = d >> 5, idx = d & 31;
    int kt = idx >> 2, dw = idx & 3;
    int w = t >> 6, l = t & 63;
    int row = w * 16 + (l & 15);
    int k0 = kt * 32 + ((l >> 4) << 3) + dw * 2;
    float e0 = R[row * NN + k0]     - (row == k0     ? 1.0f : 0.0f);
    float e1 = R[row * NN + k0 + 1] - (row == k0 + 1 ? 1.0f : 0.0f);
    Epk[d] = f2bf(e0) | (f2bf(e1) << 16);
}

// Pack w1 state-cols / 1.41 (bf16) as A-fragments for the 4 policy tiles.
// Policy thread tp = p*64 + l (p = wave-12 .. wave-15), rows p*16 + (l&15).
__global__ void k_packW(const float* __restrict__ w1, uint32* __restrict__ w1pk)
{
    int d = blockIdx.x * 256 + threadIdx.x;   // 0..8191
    int tp = d >> 5, idx = d & 31;
    int kt = idx >> 2, dw = idx & 3;
    int p = tp >> 6, l = tp & 63;
    int row = p * 16 + (l & 15);
    int k0 = kt * 32 + ((l >> 4) << 3) + dw * 2;
    const float is = 1.0f / 1.41f;
    w1pk[d] = f2bf(w1[row * 260 + k0] * is) | (f2bf(w1[row * 260 + k0 + 1] * is) << 16);
}

// ---------------- Sequential integrator (MFMA core) ----------------
// 1024 threads / 16 waves. Wave w owns output rows [16w,16w+16): 8 chained
// v_mfma_f32_16x16x32_bf16 over K=256 (A = E row-panel in 32 VGPRs, B = x'
// broadcast into all 16 cols -> every lane's 4 C values are its rows' results;
// no cross-wave combine). Waves 12-15 also run the 4 policy tiles (w1@x').
// Wave 0 finishes the (single-step-stale, R10-proven) action during Phase A,
// hidden under the other waves' MFMA work.
__global__
__attribute__((amdgpu_flat_work_group_size(1024, 1024)))
__attribute__((amdgpu_waves_per_eu(4, 4)))
void k_main(const float* __restrict__ tdata, const uint32* Epk,
            const uint32* __restrict__ w1pk, const float* __restrict__ gq,
            const float* __restrict__ w1g, const float* __restrict__ b1g,
            const float* __restrict__ w2g, float* out, int T)
{
    __shared__ __align__(16) unsigned short spk[NN];   // x' = x - MU, bf16
    __shared__ __align__(16) float hsp[2][HH];         // policy pre-activations
    __shared__ float td[2][8];
    __shared__ float aSl;

    const int t = threadIdx.x;
    const int w = t >> 6, l = t & 63;
    const int mb = w * 16 + ((l >> 4) << 2);     // this lane's 4 output rows
    const bool isPol = (w >= 12);
    const int pb = (w - 12) * 16 + ((l >> 4) << 2);
    const bool wr = ((l & 15) == 0);             // writer lanes (col 0)

    // A-frags: x-tile (8 x 4 VGPRs)
    bf16x8 ax0, ax1, ax2, ax3, ax4, ax5, ax6, ax7;
    {
        const bf16x8* Ag = reinterpret_cast<const bf16x8*>(Epk) + (size_t)t * 8;
        ax0 = Ag[0]; ax1 = Ag[1]; ax2 = Ag[2]; ax3 = Ag[3];
        ax4 = Ag[4]; ax5 = Ag[5]; ax6 = Ag[6]; ax7 = Ag[7];
    }
    // A-frags: policy tile (loaded by all waves with clamped index; used by 12-15)
    bf16x8 ap0, ap1, ap2, ap3, ap4, ap5, ap6, ap7;
    {
        int tp = isPol ? ((w - 12) * 64 + l) : 0;
        const bf16x8* Pg = reinterpret_cast<const bf16x8*>(w1pk) + (size_t)tp * 8;
        ap0 = Pg[0]; ap1 = Pg[1]; ap2 = Pg[2]; ap3 = Pg[3];
        ap4 = Pg[4]; ap5 = Pg[5]; ap6 = Pg[6]; ap7 = Pg[7];
    }
    // per-lane combine constants for rows mb..mb+3
    f32x4 G0 = *reinterpret_cast<const f32x4*>(gq + mb);
    f32x4 G1 = *reinterpret_cast<const f32x4*>(gq + 256 + mb);
    f32x4 G2 = *reinterpret_cast<const f32x4*>(gq + 512 + mb);
    f32x4 G3 = *reinterpret_cast<const f32x4*>(gq + 768 + mb);
    f32x4 Qv = *reinterpret_cast<const f32x4*>(gq + 1024 + mb);
    f32x4 CE = *reinterpret_cast<const f32x4*>(gq + 1280 + mb);
    // wave-0 action constants (per lane = hidden unit)
    float w1f0 = w1g[l * 260 + 256], w1f1 = w1g[l * 260 + 257];
    float w1f2 = w1g[l * 260 + 258], w1f3 = w1g[l * 260 + 259];
    float b1r = b1g[l], w2r = w2g[l];

    float xr0 = 26.f, xr1 = 26.f, xr2 = 26.f, xr3 = 26.f;
    if (t < NN) spk[t] = (unsigned short)f2bf(26.0f - 23.359f);
    if (t < 8) td[0][t] = tdata[t];
    __syncthreads();

    const char* spkb = reinterpret_cast<const char*>(spk);
    const int boff = (l >> 4) << 4;   // byte offset of this lane-group's k-slice

#define BFRAG(kt) (*reinterpret_cast<const bf16x8*>(spkb + (kt) * 64 + boff))

    // prologue: hsp[1] = w1@x'_0 (so k=0 action is exact policy(x_0, t_0))
    if (isPol) {
        f32x4 cp = {0.f, 0.f, 0.f, 0.f};
        cp = __builtin_amdgcn_mfma_f32_16x16x32_bf16(ap0, BFRAG(0), cp, 0, 0, 0);
        cp = __builtin_amdgcn_mfma_f32_16x16x32_bf16(ap1, BFRAG(1), cp, 0, 0, 0);
        cp = __builtin_amdgcn_mfma_f32_16x16x32_bf16(ap2, BFRAG(2), cp, 0, 0, 0);
        cp = __builtin_amdgcn_mfma_f32_16x16x32_bf16(ap3, BFRAG(3), cp, 0, 0, 0);
        cp = __builtin_amdgcn_mfma_f32_16x16x32_bf16(ap4, BFRAG(4), cp, 0, 0, 0);
        cp = __builtin_amdgcn_mfma_f32_16x16x32_bf16(ap5, BFRAG(5), cp, 0, 0, 0);
        cp = __builtin_amdgcn_mfma_f32_16x16x32_bf16(ap6, BFRAG(6), cp, 0, 0, 0);
        cp = __builtin_amdgcn_mfma_f32_16x16x32_bf16(ap7, BFRAG(7), cp, 0, 0, 0);
        if (wr) *reinterpret_cast<f32x4*>(&hsp[1][pb]) = cp;
    }
    __syncthreads();

    for (int k = 0; k < T; ++k) {
        const int cur = k & 1, nxt = cur ^ 1;
        float tdp = 0.0f;
        if (t >= 1016 && k + 1 < T) tdp = tdata[(size_t)(k + 1) * 8 + (t - 1016)];

        // ---- Phase A ----
        if (w == 0) {   // finish a_k = policy(x_{k-1}, t_k); hidden under MFMAs
            float h = tanhf(hsp[(k + 1) & 1][l] + b1r
                            + w1f0 * td[cur][4] + w1f1 * td[cur][5]
                            + w1f2 * td[cur][6] + w1f3 * td[cur][7]);
            float v = w2r * h;
            v += __shfl_xor(v, 1);  v += __shfl_xor(v, 2);  v += __shfl_xor(v, 4);
            v += __shfl_xor(v, 8);  v += __shfl_xor(v, 16); v += __shfl_xor(v, 32);
            if (l == 0) aSl = sigm(v);
        }
        // E @ x' : 8 chained MFMAs, f32 accumulation
        f32x4 cx = {0.f, 0.f, 0.f, 0.f};
        cx = __builtin_amdgcn_mfma_f32_16x16x32_bf16(ax0, BFRAG(0), cx, 0, 0, 0);
        cx = __builtin_amdgcn_mfma_f32_16x16x32_bf16(ax1, BFRAG(1), cx, 0, 0, 0);
        cx = __builtin_amdgcn_mfma_f32_16x16x32_bf16(ax2, BFRAG(2), cx, 0, 0, 0);
        cx = __builtin_amdgcn_mfma_f32_16x16x32_bf16(ax3, BFRAG(3), cx, 0, 0, 0);
        cx = __builtin_amdgcn_mfma_f32_16x16x32_bf16(ax4, BFRAG(4), cx, 0, 0, 0);
        cx = __builtin_amdgcn_mfma_f32_16x16x32_bf16(ax5, BFRAG(5), cx, 0, 0, 0);
        cx = __builtin_amdgcn_mfma_f32_16x16x32_bf16(ax6, BFRAG(6), cx, 0, 0, 0);
        cx = __builtin_amdgcn_mfma_f32_16x16x32_bf16(ax7, BFRAG(7), cx, 0, 0, 0);
        if (isPol) {   // w1 @ x' for a_{k+1}
            f32x4 cp = {0.f, 0.f, 0.f, 0.f};
            cp = __builtin_amdgcn_mfma_f32_16x16x32_bf16(ap0, BFRAG(0), cp, 0, 0, 0);
            cp = __builtin_amdgcn_mfma_f32_16x16x32_bf16(ap1, BFRAG(1), cp, 0, 0, 0);
            cp = __builtin_amdgcn_mfma_f32_16x16x32_bf16(ap2, BFRAG(2), cp, 0, 0, 0);
            cp = __builtin_amdgcn_mfma_f32_16x16x32_bf16(ap3, BFRAG(3), cp, 0, 0, 0);
            cp = __builtin_amdgcn_mfma_f32_16x16x32_bf16(ap4, BFRAG(4), cp, 0, 0, 0);
            cp = __builtin_amdgcn_mfma_f32_16x16x32_bf16(ap5, BFRAG(5), cp, 0, 0, 0);
            cp = __builtin_amdgcn_mfma_f32_16x16x32_bf16(ap6, BFRAG(6), cp, 0, 0, 0);
            cp = __builtin_amdgcn_mfma_f32_16x16x32_bf16(ap7, BFRAG(7), cp, 0, 0, 0);
            if (wr) *reinterpret_cast<f32x4*>(&hsp[cur][pb]) = cp;
        }
        if (wr) {   // emit x_k (rows mb..mb+3, 16B-aligned)
            float4 o4 = make_float4(xr0, xr1, xr2, xr3);
            *reinterpret_cast<float4*>(out + (size_t)k * NN + mb) = o4;
        }
        if (t >= 1016) td[nxt][t - 1016] = tdp;
        asm volatile("s_waitcnt lgkmcnt(0)\ns_barrier" ::: "memory");

        // ---- Phase B ----
        {
            float a = aSl;
            float S0 = td[cur][0], S1 = td[cur][1], S2 = td[cur][2], S3 = td[cur][3];
            float x0 = xr0 + cx[0] + CE[0] + S0 * G0[0] + S1 * G1[0] + S2 * G2[0] + S3 * G3[0] - a * Qv[0];
            float x1 = xr1 + cx[1] + CE[1] + S0 * G0[1] + S1 * G1[1] + S2 * G2[1] + S3 * G3[1] - a * Qv[1];
            float x2 = xr2 + cx[2] + CE[2] + S0 * G0[2] + S1 * G1[2] + S2 * G2[2] + S3 * G3[2] - a * Qv[2];
            float x3 = xr3 + cx[3] + CE[3] + S0 * G0[3] + S1 * G1[3] + S2 * G2[3] + S3 * G3[3] - a * Qv[3];
            xr0 = x0; xr1 = x1; xr2 = x2; xr3 = x3;
            if (wr) {
                uint32 d0 = f2bf(x0 - 23.359f) | (f2bf(x1 - 23.359f) << 16);
                uint32 d1 = f2bf(x2 - 23.359f) | (f2bf(x3 - 23.359f) << 16);
                *reinterpret_cast<uint2*>(reinterpret_cast<char*>(spk) + mb * 2)
                    = make_uint2(d0, d1);
            }
        }
        asm volatile("s_waitcnt lgkmcnt(0)\ns_barrier" ::: "memory");
    }
#undef BFRAG
}

extern "C" void kernel_launch(void* const* d_in, const int* in_sizes, int n_in,
                              void* d_out, int out_size, void* d_ws, size_t ws_size,
                              hipStream_t stream)
{
    (void)n_in; (void)out_size; (void)ws_size;
    const float* tev     = (const float*)d_in[0];
    const float* A       = (const float*)d_in[1];
    const float* B       = (const float*)d_in[2];
    const float* cooling = (const float*)d_in[3];
    const float* w1      = (const float*)d_in[4];
    const float* b1      = (const float*)d_in[5];
    const float* w2      = (const float*)d_in[6];
    const float* tts     = (const float*)d_in[7];
    const float* tvals   = (const float*)d_in[8];
    const int T     = in_sizes[0];
    const int ntout = in_sizes[7];

    float* out = (float*)d_out;
    float* ws  = (float*)d_ws;
    float*  R    = ws;                          // 65536 floats
    float*  gq   = ws + 65536;                  // 1536 floats
    uint32* w1pk = (uint32*)(ws + 67072);       // 8192 dwords
    float*  td   = ws + 75264;                  // T*8 floats
    float* P1 = out;                            // GEMM ping-pong (rewritten by k_main)
    float* P2 = out + 65536;
    size_t outN = (size_t)T * NN;
    uint32* Epk = (uint32*)(out + outN - 32768);  // 128 KB tail, read before overwritten

    hipLaunchKernelGGL(k_affine, dim3(256), dim3(256), 0, stream, A, P1, tev, 4);
    hipLaunchKernelGGL(k_gemm,   dim3(256), dim3(256), 0, stream, A, P1, P2, tev, 3);
    hipLaunchKernelGGL(k_gemm,   dim3(256), dim3(256), 0, stream, A, P2, P1, tev, 2);
    hipLaunchKernelGGL(k_gemm,   dim3(256), dim3(256), 0, stream, A, P1, R,  tev, 1);
    hipLaunchKernelGGL(k_packE,  dim3(128), dim3(256), 0, stream, R, Epk);
    hipLaunchKernelGGL(k_packW,  dim3(32),  dim3(256), 0, stream, w1, w1pk);
    hipLaunchKernelGGL(k_prep_vec, dim3(1), dim3(256), 0, stream, A, B, cooling, tev, R, gq);
    hipLaunchKernelGGL(k_time, dim3((T + 255) / 256), dim3(256), 0, stream,
                       tev, tts, tvals, td, T, ntout);
    hipLaunchKernelGGL(k_main, dim3(1), dim3(1024), 0, stream,
                       td, Epk, w1pk, gq, w1, b1, w2, out, T);
}

// Round 12
// 73861.530 us; speedup vs baseline: 1.0760x; 1.0760x over previous
//
#include <hip/hip_runtime.h>
#include <math.h>

#define NN 256
#define HH 64

typedef unsigned int uint32;
typedef __attribute__((ext_vector_type(8))) short bf16x8;
typedef __attribute__((ext_vector_type(4))) float f32x4;

__device__ __forceinline__ float sigm(float x) { return 1.0f / (1.0f + expf(-x)); }

// f32 -> bf16 (RNE) in low 16 bits
__device__ __forceinline__ uint32 f2bf(float f) {
    uint32 u = __float_as_uint(f);
    return (u + 0x7fffu + ((u >> 16) & 1u)) >> 16;
}

// ---------------- R construction (fp64 GEMM chain) — proven ----------------
__global__ void k_affine(const float* __restrict__ A, float* __restrict__ Pout,
                         const float* __restrict__ tev, int div)
{
    int i = blockIdx.x, j = threadIdx.x;
    double h = (double)tev[1] - (double)tev[0];
    double v = (i == j ? 1.0 : 0.0) + (h / (double)div) * (double)A[i * NN + j];
    Pout[i * NN + j] = (float)v;
}

__global__ void k_gemm(const float* __restrict__ A, const float* __restrict__ Pin,
                       float* __restrict__ Pout, const float* __restrict__ tev, int div)
{
    int i = blockIdx.x, j = threadIdx.x;
    double h = (double)tev[1] - (double)tev[0];
    const float* Ar = A + i * NN;
    double acc = 0.0;
    for (int k = 0; k < NN; ++k) acc += (double)Ar[k] * (double)Pin[k * NN + j];
    double v = (i == j ? 1.0 : 0.0) + (h / (double)div) * acc;
    Pout[i * NN + j] = (float)v;
}

// gq = [g0 | g1 | g2 | g3 | q | ce]  (ce = MU * rowsum(R - I), fp64) — proven
__global__ void k_prep_vec(const float* __restrict__ A, const float* __restrict__ B,
                           const float* __restrict__ cooling, const float* __restrict__ tev,
                           const float* __restrict__ R, float* __restrict__ gq)
{
    __shared__ float heat[NN];
    __shared__ float vin[NN];
    int t = threadIdx.x;
    double h = (double)tev[1] - (double)tev[0];
    heat[t] = (t < NN - 2) ? 500.0f * sigm(cooling[t]) : 0.0f;
    __syncthreads();
    float B0 = B[t * (NN - 1)];
    double bh = 0.0;
    for (int j = 0; j < NN - 2; ++j) bh += (double)B[t * (NN - 1) + 1 + j] * (double)heat[j];
    vin[t] = B0; __syncthreads();
    double v1 = 0.0; for (int k = 0; k < NN; ++k) v1 += (double)A[t * NN + k] * (double)vin[k];
    __syncthreads(); vin[t] = (float)v1; __syncthreads();
    double v2 = 0.0; for (int k = 0; k < NN; ++k) v2 += (double)A[t * NN + k] * (double)vin[k];
    __syncthreads(); vin[t] = (float)v2; __syncthreads();
    double v3 = 0.0; for (int k = 0; k < NN; ++k) v3 += (double)A[t * NN + k] * (double)vin[k];
    __syncthreads();
    vin[t] = (float)bh; __syncthreads();
    double u1 = 0.0; for (int k = 0; k < NN; ++k) u1 += (double)A[t * NN + k] * (double)vin[k];
    __syncthreads(); vin[t] = (float)u1; __syncthreads();
    double u2 = 0.0; for (int k = 0; k < NN; ++k) u2 += (double)A[t * NN + k] * (double)vin[k];
    __syncthreads(); vin[t] = (float)u2; __syncthreads();
    double u3 = 0.0; for (int k = 0; k < NN; ++k) u3 += (double)A[t * NN + k] * (double)vin[k];

    double srow = 0.0;
    for (int c = 0; c < NN; ++c) srow += (double)R[t * NN + c];
    srow -= 1.0;                               // rowsum(E)

    gq[t]        = (float)((h / 6.0) * (double)B0);
    gq[256 + t]  = (float)((h * h / 6.0) * v1);
    gq[512 + t]  = (float)((h * h * h / 12.0) * v2);
    gq[768 + t]  = (float)((h * h * h * h / 24.0) * v3);
    gq[1024 + t] = (float)(h * bh + (h * h / 2.0) * u1 + (h * h * h / 6.0) * u2
                           + (h * h * h * h / 24.0) * u3);
    gq[1280 + t] = (float)(23.359 * srow);
}

__device__ __forceinline__ float interp1(float x, const float* __restrict__ ts,
                                         const float* __restrict__ vs, int n)
{
    int lo = 0, hi = n;
    while (lo < hi) { int mid = (lo + hi) >> 1; if (ts[mid] <= x) lo = mid + 1; else hi = mid; }
    int i = lo; if (i < 1) i = 1; if (i > n - 1) i = n - 1;
    float xim = ts[i - 1], xi = ts[i];
    float fim = vs[i - 1], fi = vs[i];
    return fim + (x - xim) / (xi - xim) * (fi - fim);
}

// td[k][0..7] = {S0,S1,S2,S3, sinD,cosD,sinW,cosW} — proven
__global__ void k_time(const float* __restrict__ tev, const float* __restrict__ tts,
                       const float* __restrict__ tvals, float* __restrict__ td,
                       int T, int ntout)
{
    int k = blockIdx.x * blockDim.x + threadIdx.x;
    if (k >= T) return;
    float t0 = tev[0];
    float dtf = tev[1] - t0;
    float t = tev[k] - t0;
    const float cD = (float)(2.0 * M_PI / 86400.0);
    const float cW = (float)(2.0 * M_PI / 604800.0);
    float f0 = (float)sin((double)(t * cD));
    float f1 = (float)cos((double)(t * cD));
    float f2 = (float)sin((double)(t * cW));
    float f3 = (float)cos((double)(t * cW));
    float To1 = interp1(t + t0, tts, tvals, ntout);
    float To2 = interp1((t + 0.5f * dtf) + t0, tts, tvals, ntout);
    float To4 = interp1((t + dtf) + t0, tts, tvals, ntout);
    size_t o = (size_t)k * 8;
    td[o + 0] = To1 + 4.0f * To2 + To4;
    td[o + 1] = To1 + 2.0f * To2;
    td[o + 2] = To1 + To2;
    td[o + 3] = To1;
    td[o + 4] = f0; td[o + 5] = f1; td[o + 6] = f2; td[o + 7] = f3;
}

// Pack E = R - I (bf16) as MFMA A-frags, FRAGMENT-LINEAR [tile][kt][lane][4dw]
// (R11-verified frag math: lane l row = tile*16+(l&15), k = kt*32+(l>>4)*8+2j).
__global__ void k_packE(const float* __restrict__ R, uint32* __restrict__ Epk)
{
    int d = blockIdx.x * 256 + threadIdx.x;   // 0..32767
    int tile = d >> 11, kt = (d >> 8) & 7, l = (d >> 2) & 63, j = d & 3;
    int row = tile * 16 + (l & 15);
    int k0 = kt * 32 + ((l >> 4) << 3) + j * 2;
    float e0 = R[row * NN + k0]     - (row == k0     ? 1.0f : 0.0f);
    float e1 = R[row * NN + k0 + 1] - (row == k0 + 1 ? 1.0f : 0.0f);
    Epk[d] = f2bf(e0) | (f2bf(e1) << 16);
}

// Pack w1 state-cols / 1.41 (bf16) as A-frags, [tile p][kt][lane][4dw].
__global__ void k_packW(const float* __restrict__ w1, uint32* __restrict__ w1pk)
{
    int d = blockIdx.x * 256 + threadIdx.x;   // 0..8191
    int p = d >> 11, kt = (d >> 8) & 7, l = (d >> 2) & 63, j = d & 3;
    int row = p * 16 + (l & 15);
    int k0 = kt * 32 + ((l >> 4) << 3) + j * 2;
    const float is = 1.0f / 1.41f;
    w1pk[d] = f2bf(w1[row * 260 + k0] * is) | (f2bf(w1[row * 260 + k0 + 1] * is) << 16);
}

// ---------------- Sequential integrator (MFMA, LDS-resident A-frags) ----------------
// 1024 threads / 16 waves. Wave w: rows [16w,16w+16) via 8 chained
// mfma_f32_16x16x32_bf16; A-frags kt0-6 from LDS (frag-linear, conflict-free),
// kt7 in 4 VGPRs. Waves 12-15 also run the 4 policy tiles (frags in LDS).
// ~45 VGPRs/thread -> no spill possible. Stale action (R10/R11-proven).
__global__
__attribute__((amdgpu_flat_work_group_size(1024, 1024)))
void k_main(const float* __restrict__ tdata, const uint32* Epk,
            const uint32* __restrict__ w1pk, const float* __restrict__ gq,
            const float* __restrict__ w1g, const float* __restrict__ b1g,
            const float* __restrict__ w2g, float* out, int T)
{
    __shared__ __align__(16) uint32 ldsE[16 * 7 * 256];  // 114688 B
    __shared__ __align__(16) uint32 ldsP[4 * 8 * 256];   // 32768 B
    __shared__ __align__(16) float gql[6 * NN];          // 6144 B
    __shared__ __align__(16) unsigned short spk[NN];     // x' bf16, 512 B
    __shared__ __align__(16) float hsp[2][HH];
    __shared__ float td[2][8];
    __shared__ float aSl;

    const int t = threadIdx.x;
    const int w = t >> 6, l = t & 63;
    const int mb = w * 16 + ((l >> 4) << 2);     // this lane's 4 output rows
    const bool isPol = (w >= 12);
    const int p = w - 12;
    const int pb = p * 16 + ((l >> 4) << 2);
    const bool wr = ((l & 15) == 0);             // writer lanes (col 0)

    // one-time LDS fills
    for (int i = t; i < 16 * 7 * 256; i += 1024) {
        int tile = i / 1792, rem = i - tile * 1792;   // kt0-6 region of each tile
        ldsE[i] = Epk[tile * 2048 + rem];
    }
    for (int i = t; i < 4 * 8 * 256; i += 1024) ldsP[i] = w1pk[i];
    for (int i = t; i < 6 * NN; i += 1024) gql[i] = gq[i];
    // kt7 E-frag -> 4 VGPRs
    bf16x8 ax7 = reinterpret_cast<const bf16x8*>(Epk)[w * 512 + 448 + l];
    // wave-0 action constants
    float w1f0 = w1g[l * 260 + 256], w1f1 = w1g[l * 260 + 257];
    float w1f2 = w1g[l * 260 + 258], w1f3 = w1g[l * 260 + 259];
    float b1r = b1g[l], w2r = w2g[l];

    float xr0 = 26.f, xr1 = 26.f, xr2 = 26.f, xr3 = 26.f;
    if (t < NN) spk[t] = (unsigned short)f2bf(26.0f - 23.359f);
    if (t < 8) td[0][t] = tdata[t];
    __syncthreads();

    const char* spkb = reinterpret_cast<const char*>(spk);
    const int boff = (l >> 4) << 4;   // this lane-group's k-slice byte offset
    const bf16x8* fE = reinterpret_cast<const bf16x8*>(ldsE) + w * 7 * 64 + l;
    const bf16x8* fP = reinterpret_cast<const bf16x8*>(ldsP) + p * 8 * 64 + l;

#define BFRAG(kt) (*reinterpret_cast<const bf16x8*>(spkb + (kt) * 64 + boff))

    // prologue: hsp[1] = w1 @ x'_0  (a_0 exact)
    if (isPol) {
        f32x4 cp = {0.f, 0.f, 0.f, 0.f};
        #pragma unroll
        for (int kt = 0; kt < 8; ++kt)
            cp = __builtin_amdgcn_mfma_f32_16x16x32_bf16(fP[kt * 64], BFRAG(kt), cp, 0, 0, 0);
        if (wr) *reinterpret_cast<f32x4*>(&hsp[1][pb]) = cp;
    }
    __syncthreads();

    for (int k = 0; k < T; ++k) {
        const int cur = k & 1, nxt = cur ^ 1;
        float tdp = 0.0f;
        if (t >= 1016 && k + 1 < T) tdp = tdata[(size_t)(k + 1) * 8 + (t - 1016)];

        // ---- Phase A ----
        if (w == 0) {   // finish a_k = policy(x_{k-1}, t_k), hidden under MFMAs
            float h = tanhf(hsp[nxt][l] + b1r
                            + w1f0 * td[cur][4] + w1f1 * td[cur][5]
                            + w1f2 * td[cur][6] + w1f3 * td[cur][7]);
            float v = w2r * h;
            v += __shfl_xor(v, 1);  v += __shfl_xor(v, 2);  v += __shfl_xor(v, 4);
            v += __shfl_xor(v, 8);  v += __shfl_xor(v, 16); v += __shfl_xor(v, 32);
            if (l == 0) aSl = sigm(v);
        }
        // E @ x' : kt0-6 frags from LDS, kt7 from regs
        f32x4 cx = {0.f, 0.f, 0.f, 0.f};
        #pragma unroll
        for (int kt = 0; kt < 7; ++kt)
            cx = __builtin_amdgcn_mfma_f32_16x16x32_bf16(fE[kt * 64], BFRAG(kt), cx, 0, 0, 0);
        cx = __builtin_amdgcn_mfma_f32_16x16x32_bf16(ax7, BFRAG(7), cx, 0, 0, 0);
        if (isPol) {    // w1 @ x'_k for a_{k+1}
            f32x4 cp = {0.f, 0.f, 0.f, 0.f};
            #pragma unroll
            for (int kt = 0; kt < 8; ++kt)
                cp = __builtin_amdgcn_mfma_f32_16x16x32_bf16(fP[kt * 64], BFRAG(kt), cp, 0, 0, 0);
            if (wr) *reinterpret_cast<f32x4*>(&hsp[cur][pb]) = cp;
        }
        if (wr)
            *reinterpret_cast<float4*>(out + (size_t)k * NN + mb)
                = make_float4(xr0, xr1, xr2, xr3);
        if (t >= 1016) td[nxt][t - 1016] = tdp;
        asm volatile("s_waitcnt lgkmcnt(0)\ns_barrier" ::: "memory");

        // ---- Phase B (writer lanes only) ----
        if (wr) {
            const f32x4* g4 = reinterpret_cast<const f32x4*>(gql);
            int b = mb >> 2;
            f32x4 G0 = g4[b], G1 = g4[64 + b], G2 = g4[128 + b], G3 = g4[192 + b];
            f32x4 Qv = g4[256 + b], CE = g4[320 + b];
            float a = aSl;
            float S0 = td[cur][0], S1 = td[cur][1], S2 = td[cur][2], S3 = td[cur][3];
            float x0 = xr0 + cx[0] + CE[0] + S0 * G0[0] + S1 * G1[0] + S2 * G2[0] + S3 * G3[0] - a * Qv[0];
            float x1 = xr1 + cx[1] + CE[1] + S0 * G0[1] + S1 * G1[1] + S2 * G2[1] + S3 * G3[1] - a * Qv[1];
            float x2 = xr2 + cx[2] + CE[2] + S0 * G0[2] + S1 * G1[2] + S2 * G2[2] + S3 * G3[2] - a * Qv[2];
            float x3 = xr3 + cx[3] + CE[3] + S0 * G0[3] + S1 * G1[3] + S2 * G2[3] + S3 * G3[3] - a * Qv[3];
            xr0 = x0; xr1 = x1; xr2 = x2; xr3 = x3;
            uint32 d0 = f2bf(x0 - 23.359f) | (f2bf(x1 - 23.359f) << 16);
            uint32 d1 = f2bf(x2 - 23.359f) | (f2bf(x3 - 23.359f) << 16);
            *reinterpret_cast<uint2*>(reinterpret_cast<char*>(spk) + mb * 2)
                = make_uint2(d0, d1);
        }
        asm volatile("s_waitcnt lgkmcnt(0)\ns_barrier" ::: "memory");
    }
#undef BFRAG
}

extern "C" void kernel_launch(void* const* d_in, const int* in_sizes, int n_in,
                              void* d_out, int out_size, void* d_ws, size_t ws_size,
                              hipStream_t stream)
{
    (void)n_in; (void)out_size; (void)ws_size;
    const float* tev     = (const float*)d_in[0];
    const float* A       = (const float*)d_in[1];
    const float* B       = (const float*)d_in[2];
    const float* cooling = (const float*)d_in[3];
    const float* w1      = (const float*)d_in[4];
    const float* b1      = (const float*)d_in[5];
    const float* w2      = (const float*)d_in[6];
    const float* tts     = (const float*)d_in[7];
    const float* tvals   = (const float*)d_in[8];
    const int T     = in_sizes[0];
    const int ntout = in_sizes[7];

    float* out = (float*)d_out;
    float* ws  = (float*)d_ws;
    float*  R    = ws;                          // 65536 floats
    float*  gq   = ws + 65536;                  // 1536 floats
    uint32* w1pk = (uint32*)(ws + 67072);       // 8192 dwords
    float*  td   = ws + 75264;                  // T*8 floats
    float* P1 = out;                            // GEMM ping-pong (rewritten by k_main)
    float* P2 = out + 65536;
    size_t outN = (size_t)T * NN;
    uint32* Epk = (uint32*)(out + outN - 32768);  // 128 KB tail, read before overwritten

    hipLaunchKernelGGL(k_affine, dim3(256), dim3(256), 0, stream, A, P1, tev, 4);
    hipLaunchKernelGGL(k_gemm,   dim3(256), dim3(256), 0, stream, A, P1, P2, tev, 3);
    hipLaunchKernelGGL(k_gemm,   dim3(256), dim3(256), 0, stream, A, P2, P1, tev, 2);
    hipLaunchKernelGGL(k_gemm,   dim3(256), dim3(256), 0, stream, A, P1, R,  tev, 1);
    hipLaunchKernelGGL(k_packE,  dim3(128), dim3(256), 0, stream, R, Epk);
    hipLaunchKernelGGL(k_packW,  dim3(32),  dim3(256), 0, stream, w1, w1pk);
    hipLaunchKernelGGL(k_prep_vec, dim3(1), dim3(256), 0, stream, A, B, cooling, tev, R, gq);
    hipLaunchKernelGGL(k_time, dim3((T + 255) / 256), dim3(256), 0, stream,
                       tev, tts, tvals, td, T, ntout);
    hipLaunchKernelGGL(k_main, dim3(1), dim3(1024), 0, stream,
                       td, Epk, w1pk, gq, w1, b1, w2, out, T);
}

// Round 13
// 61563.318 us; speedup vs baseline: 1.2909x; 1.1998x over previous
//
#include <hip/hip_runtime.h>
#include <hip/hip_fp16.h>
#include <math.h>

#define NN 256
#define HH 64

typedef unsigned int uint32;
typedef __attribute__((ext_vector_type(8))) short bf16x8;
typedef __attribute__((ext_vector_type(4))) float f32x4;

__device__ __forceinline__ float sigm(float x) { return 1.0f / (1.0f + expf(-x)); }

// f32 -> bf16 (RNE) in low 16 bits
__device__ __forceinline__ uint32 f2bf(float f) {
    uint32 u = __float_as_uint(f);
    return (u + 0x7fffu + ((u >> 16) & 1u)) >> 16;
}

// packed f16 FMA: 2 MACs in one v_pk_fma_f16 (R10-proven)
__device__ __forceinline__ __half2 pkfma(uint32 a, uint32 b, __half2 c) {
    __half2 x = *reinterpret_cast<__half2*>(&a);
    __half2 y = *reinterpret_cast<__half2*>(&b);
    return __hfma2(x, y, c);
}

// ---------------- R construction (fp64 GEMM chain) — proven ----------------
__global__ void k_affine(const float* __restrict__ A, float* __restrict__ Pout,
                         const float* __restrict__ tev, int div)
{
    int i = blockIdx.x, j = threadIdx.x;
    double h = (double)tev[1] - (double)tev[0];
    double v = (i == j ? 1.0 : 0.0) + (h / (double)div) * (double)A[i * NN + j];
    Pout[i * NN + j] = (float)v;
}

__global__ void k_gemm(const float* __restrict__ A, const float* __restrict__ Pin,
                       float* __restrict__ Pout, const float* __restrict__ tev, int div)
{
    int i = blockIdx.x, j = threadIdx.x;
    double h = (double)tev[1] - (double)tev[0];
    const float* Ar = A + i * NN;
    double acc = 0.0;
    for (int k = 0; k < NN; ++k) acc += (double)Ar[k] * (double)Pin[k * NN + j];
    double v = (i == j ? 1.0 : 0.0) + (h / (double)div) * acc;
    Pout[i * NN + j] = (float)v;
}

// gq = [g0 | g1 | g2 | g3 | q | ce]  (ce = MU * rowsum(R - I), fp64) — proven
__global__ void k_prep_vec(const float* __restrict__ A, const float* __restrict__ B,
                           const float* __restrict__ cooling, const float* __restrict__ tev,
                           const float* __restrict__ R, float* __restrict__ gq)
{
    __shared__ float heat[NN];
    __shared__ float vin[NN];
    int t = threadIdx.x;
    double h = (double)tev[1] - (double)tev[0];
    heat[t] = (t < NN - 2) ? 500.0f * sigm(cooling[t]) : 0.0f;
    __syncthreads();
    float B0 = B[t * (NN - 1)];
    double bh = 0.0;
    for (int j = 0; j < NN - 2; ++j) bh += (double)B[t * (NN - 1) + 1 + j] * (double)heat[j];
    vin[t] = B0; __syncthreads();
    double v1 = 0.0; for (int k = 0; k < NN; ++k) v1 += (double)A[t * NN + k] * (double)vin[k];
    __syncthreads(); vin[t] = (float)v1; __syncthreads();
    double v2 = 0.0; for (int k = 0; k < NN; ++k) v2 += (double)A[t * NN + k] * (double)vin[k];
    __syncthreads(); vin[t] = (float)v2; __syncthreads();
    double v3 = 0.0; for (int k = 0; k < NN; ++k) v3 += (double)A[t * NN + k] * (double)vin[k];
    __syncthreads();
    vin[t] = (float)bh; __syncthreads();
    double u1 = 0.0; for (int k = 0; k < NN; ++k) u1 += (double)A[t * NN + k] * (double)vin[k];
    __syncthreads(); vin[t] = (float)u1; __syncthreads();
    double u2 = 0.0; for (int k = 0; k < NN; ++k) u2 += (double)A[t * NN + k] * (double)vin[k];
    __syncthreads(); vin[t] = (float)u2; __syncthreads();
    double u3 = 0.0; for (int k = 0; k < NN; ++k) u3 += (double)A[t * NN + k] * (double)vin[k];

    double srow = 0.0;
    for (int c = 0; c < NN; ++c) srow += (double)R[t * NN + c];
    srow -= 1.0;                               // rowsum(E)

    gq[t]        = (float)((h / 6.0) * (double)B0);
    gq[256 + t]  = (float)((h * h / 6.0) * v1);
    gq[512 + t]  = (float)((h * h * h / 12.0) * v2);
    gq[768 + t]  = (float)((h * h * h * h / 24.0) * v3);
    gq[1024 + t] = (float)(h * bh + (h * h / 2.0) * u1 + (h * h * h / 6.0) * u2
                           + (h * h * h * h / 24.0) * u3);
    gq[1280 + t] = (float)(23.359 * srow);
}

__device__ __forceinline__ float interp1(float x, const float* __restrict__ ts,
                                         const float* __restrict__ vs, int n)
{
    int lo = 0, hi = n;
    while (lo < hi) { int mid = (lo + hi) >> 1; if (ts[mid] <= x) lo = mid + 1; else hi = mid; }
    int i = lo; if (i < 1) i = 1; if (i > n - 1) i = n - 1;
    float xim = ts[i - 1], xi = ts[i];
    float fim = vs[i - 1], fi = vs[i];
    return fim + (x - xim) / (xi - xim) * (fi - fim);
}

// td[k][0..7] = {S0,S1,S2,S3, sinD,cosD,sinW,cosW} — proven
__global__ void k_time(const float* __restrict__ tev, const float* __restrict__ tts,
                       const float* __restrict__ tvals, float* __restrict__ td,
                       int T, int ntout)
{
    int k = blockIdx.x * blockDim.x + threadIdx.x;
    if (k >= T) return;
    float t0 = tev[0];
    float dtf = tev[1] - t0;
    float t = tev[k] - t0;
    const float cD = (float)(2.0 * M_PI / 86400.0);
    const float cW = (float)(2.0 * M_PI / 604800.0);
    float f0 = (float)sin((double)(t * cD));
    float f1 = (float)cos((double)(t * cD));
    float f2 = (float)sin((double)(t * cW));
    float f3 = (float)cos((double)(t * cW));
    float To1 = interp1(t + t0, tts, tvals, ntout);
    float To2 = interp1((t + 0.5f * dtf) + t0, tts, tvals, ntout);
    float To4 = interp1((t + dtf) + t0, tts, tvals, ntout);
    size_t o = (size_t)k * 8;
    td[o + 0] = To1 + 4.0f * To2 + To4;
    td[o + 1] = To1 + 2.0f * To2;
    td[o + 2] = To1 + To2;
    td[o + 3] = To1;
    td[o + 4] = f0; td[o + 5] = f1; td[o + 6] = f2; td[o + 7] = f3;
}

// Pack E = R - I (bf16) as MFMA A-frags, per-thread layout (R11-verified):
// thread t (w=t>>6, l=t&63): row = 16w+(l&15); Epk[t*32+kt*4+dw] packs
// k0 = kt*32+(l>>4)*8+2dw, k0+1.
__global__ void k_packE(const float* __restrict__ R, uint32* __restrict__ Epk)
{
    int d = blockIdx.x * 256 + threadIdx.x;   // 0..32767
    int t = d >> 5, idx = d & 31;
    int kt = idx >> 2, dw = idx & 3;
    int w = t >> 6, l = t & 63;
    int row = w * 16 + (l & 15);
    int k0 = kt * 32 + ((l >> 4) << 3) + dw * 2;
    float e0 = R[row * NN + k0]     - (row == k0     ? 1.0f : 0.0f);
    float e1 = R[row * NN + k0 + 1] - (row == k0 + 1 ? 1.0f : 0.0f);
    Epk[d] = f2bf(e0) | (f2bf(e1) << 16);
}

// Pack w1 state-cols / 1.41 as f16 pairs, bank-swizzled 16B chunks:
// chunk P = (jr*32 + c*2 + q) ^ (jr&7); dword P*4+di holds cols
// 16c + q*8 + 2di, +1  (reader: thread (jr,c) reads chunks P(q=0),P(q=1)).
__global__ void k_packW(const float* __restrict__ w1, uint32* __restrict__ w1pk)
{
    int d = blockIdx.x * 256 + threadIdx.x;   // 0..8191
    int jr = d >> 7, rem = d & 127;
    int c = rem >> 3, q = (rem >> 2) & 1, di = rem & 3;
    int col = 16 * c + q * 8 + 2 * di;
    int P = (jr * 32 + c * 2 + q) ^ (jr & 7);
    const float is = 1.0f / 1.41f;
    union { _Float16 h[2]; uint32 u; } p;
    p.h[0] = (_Float16)(w1[jr * 260 + col] * is);
    p.h[1] = (_Float16)(w1[jr * 260 + col + 1] * is);
    w1pk[P * 4 + di] = p.u;
}

// ---------------- Sequential integrator ----------------
// 1024 threads / 16 waves. Wave w: output rows [16w,16w+16) via 8 chained
// mfma_f32_16x16x32_bf16; A-frags in 32 VGPRs/thread (R4-proven budget);
// B = x' bf16 broadcast from LDS (conflict-free 4-addr reads).
// Policy hidden layer on VALU: 1024 threads x 16 cols (pk_fma_f16), w1 in
// swizzled LDS. Stale action (R10/R11/R12-proven): a_k = policy(x_{k-1},t_k).
__global__
__attribute__((amdgpu_flat_work_group_size(1024, 1024)))
void k_main(const float* __restrict__ tdata, const uint32* Epk,
            const uint32* __restrict__ w1pk, const float* __restrict__ gq,
            const float* __restrict__ w1g, const float* __restrict__ b1g,
            const float* __restrict__ w2g, float* out, int T)
{
    __shared__ __align__(16) uint32 w1l[8192];          // 32 KB, swizzled
    __shared__ __align__(16) unsigned short spk[NN];    // x' bf16 (BFRAG source)
    __shared__ __align__(16) unsigned short spkh[NN];   // x' f16, 16B-interleaved
    __shared__ __align__(16) float part[NN];
    __shared__ __align__(16) float hsp[2][HH];
    __shared__ float wf[6 * HH];                        // w1f0..3, b1, w2
    __shared__ float td[2][8];
    __shared__ float aSl;

    const int t = threadIdx.x;
    const int w = t >> 6, l = t & 63;
    const int mb = w * 16 + ((l >> 4) << 2);     // lane's 4 output rows
    const bool wrt = ((l & 15) == 0);            // C-col-0 lanes
    const int jr = t >> 4, c = t & 15;           // policy row / col-chunk
    const int r = t & 255;

    // E A-frags -> 32 VGPRs (R4-proven residency at this budget)
    bf16x8 ax0, ax1, ax2, ax3, ax4, ax5, ax6, ax7;
    {
        const bf16x8* Ag = reinterpret_cast<const bf16x8*>(Epk) + (size_t)t * 8;
        ax0 = Ag[0]; ax1 = Ag[1]; ax2 = Ag[2]; ax3 = Ag[3];
        ax4 = Ag[4]; ax5 = Ag[5]; ax6 = Ag[6]; ax7 = Ag[7];
    }
    // per-row combine constants (meaningful for t<256)
    float g0r = gq[r], g1r = gq[256 + r], g2r = gq[512 + r], g3r = gq[768 + r];
    float qr = gq[1024 + r], cer = gq[1280 + r];

    for (int i = t; i < 8192; i += 1024) w1l[i] = w1pk[i];
    if (t < HH) {
        wf[t]       = w1g[t * 260 + 256];
        wf[64 + t]  = w1g[t * 260 + 257];
        wf[128 + t] = w1g[t * 260 + 258];
        wf[192 + t] = w1g[t * 260 + 259];
        wf[256 + t] = b1g[t];
        wf[320 + t] = w2g[t];
    }
    float xr = 26.0f;
    if (t < NN) {
        spk[t] = (unsigned short)f2bf(26.0f - 23.359f);
        _Float16 hv = (_Float16)(26.0f - 23.359f);
        int p = (((t >> 3) & 1) << 4) + (t >> 4);          // chunk interleave
        spkh[p * 8 + (t & 7)] = __builtin_bit_cast(unsigned short, hv);
    }
    if (t < 8) td[0][t] = tdata[t];
    __syncthreads();

    const char* spkb = reinterpret_cast<const char*>(spk);
    const int boff = (l >> 4) << 4;
    const uint4* w1l4 = reinterpret_cast<const uint4*>(w1l);
    const uint4* sh4 = reinterpret_cast<const uint4*>(spkh);
    const int P0 = (jr * 32 + c * 2) ^ (jr & 7);
    const int P1 = (jr * 32 + c * 2 + 1) ^ (jr & 7);
    const __half2 hzero = __floats2half2_rn(0.0f, 0.0f);

#define BFRAG(kt) (*reinterpret_cast<const bf16x8*>(spkb + (kt) * 64 + boff))
#define POLICY_DOT(dst)                                                        \
    {                                                                          \
        uint4 wq0 = w1l4[P0], wq1 = w1l4[P1];                                  \
        uint4 sq0 = sh4[c], sq1 = sh4[16 + c];                                 \
        __half2 a0 = hzero, a1 = hzero;                                        \
        a0 = pkfma(wq0.x, sq0.x, a0); a1 = pkfma(wq0.y, sq0.y, a1);            \
        a0 = pkfma(wq0.z, sq0.z, a0); a1 = pkfma(wq0.w, sq0.w, a1);            \
        a0 = pkfma(wq1.x, sq1.x, a0); a1 = pkfma(wq1.y, sq1.y, a1);            \
        a0 = pkfma(wq1.z, sq1.z, a0); a1 = pkfma(wq1.w, sq1.w, a1);            \
        float hs = __low2float(a0) + __high2float(a0)                          \
                 + __low2float(a1) + __high2float(a1);                         \
        hs += __shfl_xor(hs, 1); hs += __shfl_xor(hs, 2);                      \
        hs += __shfl_xor(hs, 4); hs += __shfl_xor(hs, 8);                      \
        if (c == 0) dst = hs;                                                  \
    }

    // prologue: hsp[1] = w1 @ x'_0  (a_0 exact = policy(x_0, t_0))
    POLICY_DOT(hsp[1][jr])
    __syncthreads();

    for (int k = 0; k < T; ++k) {
        const int cur = k & 1, nxt = cur ^ 1;
        float tdp = 0.0f;
        if (t >= 1016 && k + 1 < T) tdp = tdata[(size_t)(k + 1) * 8 + (t - 1016)];

        // ---- Phase A ----
        if (w == 0) {   // finish a_k from hsp[prev] + features(t_k); hidden
            float h = tanhf(hsp[nxt][l] + wf[256 + l]
                            + wf[l] * td[cur][4] + wf[64 + l] * td[cur][5]
                            + wf[128 + l] * td[cur][6] + wf[192 + l] * td[cur][7]);
            float v = wf[320 + l] * h;
            v += __shfl_xor(v, 1);  v += __shfl_xor(v, 2);  v += __shfl_xor(v, 4);
            v += __shfl_xor(v, 8);  v += __shfl_xor(v, 16); v += __shfl_xor(v, 32);
            if (l == 0) aSl = sigm(v);
        }
        // policy partials from x'_k (feeds a_{k+1}) — all 1024 threads
        POLICY_DOT(hsp[cur][jr])
        // E @ x'_k : 8 chained MFMAs, f32 accumulation
        {
            f32x4 cx = {0.f, 0.f, 0.f, 0.f};
            cx = __builtin_amdgcn_mfma_f32_16x16x32_bf16(ax0, BFRAG(0), cx, 0, 0, 0);
            cx = __builtin_amdgcn_mfma_f32_16x16x32_bf16(ax1, BFRAG(1), cx, 0, 0, 0);
            cx = __builtin_amdgcn_mfma_f32_16x16x32_bf16(ax2, BFRAG(2), cx, 0, 0, 0);
            cx = __builtin_amdgcn_mfma_f32_16x16x32_bf16(ax3, BFRAG(3), cx, 0, 0, 0);
            cx = __builtin_amdgcn_mfma_f32_16x16x32_bf16(ax4, BFRAG(4), cx, 0, 0, 0);
            cx = __builtin_amdgcn_mfma_f32_16x16x32_bf16(ax5, BFRAG(5), cx, 0, 0, 0);
            cx = __builtin_amdgcn_mfma_f32_16x16x32_bf16(ax6, BFRAG(6), cx, 0, 0, 0);
            cx = __builtin_amdgcn_mfma_f32_16x16x32_bf16(ax7, BFRAG(7), cx, 0, 0, 0);
            if (wrt) *reinterpret_cast<f32x4*>(&part[mb]) = cx;
        }
        if (t < NN) out[(size_t)k * NN + t] = xr;
        if (t >= 1016) td[nxt][t - 1016] = tdp;
        asm volatile("s_waitcnt lgkmcnt(0)\ns_barrier" ::: "memory");

        // ---- Phase B: x_{k+1} = x_k + E@x' + ce + S·g − a_k·q ----
        if (t < NN) {
            float a = aSl;
            float S0 = td[cur][0], S1 = td[cur][1], S2 = td[cur][2], S3 = td[cur][3];
            float xn = xr + part[t] + cer
                     + S0 * g0r + S1 * g1r + S2 * g2r + S3 * g3r - a * qr;
            xr = xn;
            float xp = xn - 23.359f;
            spk[t] = (unsigned short)f2bf(xp);
            _Float16 hv = (_Float16)xp;
            int p = (((t >> 3) & 1) << 4) + (t >> 4);
            spkh[p * 8 + (t & 7)] = __builtin_bit_cast(unsigned short, hv);
        }
        asm volatile("s_waitcnt lgkmcnt(0)\ns_barrier" ::: "memory");
    }
#undef BFRAG
#undef POLICY_DOT
}

extern "C" void kernel_launch(void* const* d_in, const int* in_sizes, int n_in,
                              void* d_out, int out_size, void* d_ws, size_t ws_size,
                              hipStream_t stream)
{
    (void)n_in; (void)out_size; (void)ws_size;
    const float* tev     = (const float*)d_in[0];
    const float* A       = (const float*)d_in[1];
    const float* B       = (const float*)d_in[2];
    const float* cooling = (const float*)d_in[3];
    const float* w1      = (const float*)d_in[4];
    const float* b1      = (const float*)d_in[5];
    const float* w2      = (const float*)d_in[6];
    const float* tts     = (const float*)d_in[7];
    const float* tvals   = (const float*)d_in[8];
    const int T     = in_sizes[0];
    const int ntout = in_sizes[7];

    float* out = (float*)d_out;
    float* ws  = (float*)d_ws;
    float*  R    = ws;                          // 65536 floats
    float*  gq   = ws + 65536;                  // 1536 floats
    uint32* w1pk = (uint32*)(ws + 67072);       // 8192 dwords
    float*  td   = ws + 75264;                  // T*8 floats
    float* P1 = out;                            // GEMM ping-pong (rewritten by k_main)
    float* P2 = out + 65536;
    size_t outN = (size_t)T * NN;
    uint32* Epk = (uint32*)(out + outN - 32768);  // 128 KB tail, read before overwritten

    hipLaunchKernelGGL(k_affine, dim3(256), dim3(256), 0, stream, A, P1, tev, 4);
    hipLaunchKernelGGL(k_gemm,   dim3(256), dim3(256), 0, stream, A, P1, P2, tev, 3);
    hipLaunchKernelGGL(k_gemm,   dim3(256), dim3(256), 0, stream, A, P2, P1, tev, 2);
    hipLaunchKernelGGL(k_gemm,   dim3(256), dim3(256), 0, stream, A, P1, R,  tev, 1);
    hipLaunchKernelGGL(k_packE,  dim3(128), dim3(256), 0, stream, R, Epk);
    hipLaunchKernelGGL(k_packW,  dim3(32),  dim3(256), 0, stream, w1, w1pk);
    hipLaunchKernelGGL(k_prep_vec, dim3(1), dim3(256), 0, stream, A, B, cooling, tev, R, gq);
    hipLaunchKernelGGL(k_time, dim3((T + 255) / 256), dim3(256), 0, stream,
                       tev, tts, tvals, td, T, ntout);
    hipLaunchKernelGGL(k_main, dim3(1), dim3(1024), 0, stream,
                       td, Epk, w1pk, gq, w1, b1, w2, out, T);
}